// Round 3
// baseline (28.210 us; speedup 1.0000x reference)
//
#include <hip/hip_runtime.h>
#include <hip/hip_bf16.h>
#include <math.h>

namespace {

typedef __bf16 bf16x8 __attribute__((ext_vector_type(8)));
typedef float f32x4 __attribute__((ext_vector_type(4)));

constexpr int L = 64;
constexpr int DH = 64;

// Byte offset of bf16 element (row,col) in a 64x64 row-major bf16 LDS tile
// (row stride 128 B) with a 16B-slot XOR swizzle (T2; both-sides-or-neither).
__device__ __forceinline__ int swz(int row, int col) {
  return row * 128 + (((col >> 3) ^ (row & 7)) << 4) + (col & 7) * 2;
}

__device__ __forceinline__ unsigned short bfbits(float f) {
  __bf16 h = (__bf16)f;
  return __builtin_bit_cast(unsigned short, h);
}
__device__ __forceinline__ __bf16 tobf(float f) { return (__bf16)f; }

__global__ __launch_bounds__(64) void mlstm_mfma(
    const float* __restrict__ q, const float* __restrict__ k,
    const float* __restrict__ v, const float* __restrict__ ig,
    const float* __restrict__ fg, float* __restrict__ out) {

  // One wave owns one 64x64 chunk; no barriers. ONE 8KB tile buffer:
  // holds V^T (bf16, swizzled) first, then is overwritten with C after
  // the V fragments have been pulled into registers (DS ops are in-order
  // within a wave; same-array accesses keep the WAR order).
  __shared__ __align__(16) char tile[64 * 128];
  __shared__ float ea_sh[64], eb_sh[64], em_sh[64];

  const int lane = threadIdx.x;
  const int m = lane & 15;   // fragment row/col index
  const int g = lane >> 4;   // fragment k-group
  const size_t cbase = (size_t)blockIdx.x * (L * DH);
  const size_t gb = (size_t)blockIdx.x * L;

  // ---- issue ALL global loads up front (gates -> v -> q/k) --------------
  const float fgv = fg[gb + lane];
  const float igv = ig[gb + lane];

  const float4* v4 = (const float4*)(v + cbase);
  float4 vbuf[16];
#pragma unroll
  for (int it = 0; it < 16; ++it) vbuf[it] = v4[it * 64 + lane];

  // Q,K fragments: global -> registers, cvt bf16.
  // mm1 computes S^T = K * Q^T; both operands natural row-major.
  bf16x8 kf[4][2], qf[4][2];
#pragma unroll
  for (int rb = 0; rb < 4; ++rb)
#pragma unroll
    for (int kb = 0; kb < 2; ++kb) {
      const int off = (rb * 16 + m) * 64 + kb * 32 + g * 8;
      const float4 k0 = *(const float4*)(k + cbase + off);
      const float4 k1 = *(const float4*)(k + cbase + off + 4);
      const float4 q0 = *(const float4*)(q + cbase + off);
      const float4 q1 = *(const float4*)(q + cbase + off + 4);
      kf[rb][kb] = bf16x8{tobf(k0.x), tobf(k0.y), tobf(k0.z), tobf(k0.w),
                          tobf(k1.x), tobf(k1.y), tobf(k1.z), tobf(k1.w)};
      qf[rb][kb] = bf16x8{tobf(q0.x), tobf(q0.y), tobf(q0.z), tobf(q0.w),
                          tobf(q1.x), tobf(q1.y), tobf(q1.z), tobf(q1.w)};
    }

  // ---- gates: two 64-lane scans, 3 exps per lane -------------------------
  {
    const float lf = fminf(fgv, 0.f) - log1pf(__expf(-fabsf(fgv)));
    float cum = lf;  // inclusive prefix sum of log f
#pragma unroll
    for (int o = 1; o < 64; o <<= 1) {
      const float t = __shfl_up(cum, o, 64);
      if (lane >= o) cum += t;
    }
    const float a = igv - cum;  // a[j] = ig[j] - cum[j]
    float b = a;                // b[i] = prefix max of a
#pragma unroll
    for (int o = 1; o < 64; o <<= 1) {
      const float t = __shfl_up(b, o, 64);
      if (lane >= o) b = fmaxf(b, t);
    }
    const float bmax = __shfl(b, 63, 64);
    ea_sh[lane] = 0.125f * __expf(a - bmax);  // fold 1/sqrt(DH)
    eb_sh[lane] = __expf(bmax - b);
    em_sh[lane] = __expf(-(b + cum));
  }

  // ---- stage V^T into LDS tile (bf16, swizzled scatter) ------------------
  {
    unsigned short* vt = (unsigned short*)tile;
#pragma unroll
    for (int it = 0; it < 16; ++it) {
      const int idx = it * 64 + lane;  // float4 index in the chunk
      const int j = idx >> 4;          // source row (time)
      const int d0 = (idx & 15) * 4;   // source col (feature)
      vt[swz(d0 + 0, j) >> 1] = bfbits(vbuf[it].x);
      vt[swz(d0 + 1, j) >> 1] = bfbits(vbuf[it].y);
      vt[swz(d0 + 2, j) >> 1] = bfbits(vbuf[it].z);
      vt[swz(d0 + 3, j) >> 1] = bfbits(vbuf[it].w);
    }
  }

  // ---- pull V^T fragments into registers NOW (tile is reused for C) ------
  bf16x8 vfr[4][2];
#pragma unroll
  for (int db = 0; db < 4; ++db)
#pragma unroll
    for (int jb = 0; jb < 2; ++jb)
      vfr[db][jb] = *(const bf16x8*)(tile + swz(db * 16 + m, jb * 32 + g * 8));

  // ---- mm1: S^T tiles (only rb <= cb are causal) --------------------------
  f32x4 st[4][4];
#pragma unroll
  for (int cb = 0; cb < 4; ++cb)
#pragma unroll
    for (int rb = 0; rb < 4; ++rb) {
      if (rb > cb) continue;
      f32x4 acc = {0.f, 0.f, 0.f, 0.f};
      acc = __builtin_amdgcn_mfma_f32_16x16x32_bf16(kf[rb][0], qf[cb][0], acc, 0, 0, 0);
      acc = __builtin_amdgcn_mfma_f32_16x16x32_bf16(kf[rb][1], qf[cb][1], acc, 0, 0, 0);
      st[rb][cb] = acc;
    }

  // ---- gating, row-sum, normalizer; write C (bf16) into tile --------------
  float ea_j[4][4];
#pragma unroll
  for (int rb = 0; rb < 4; ++rb)
#pragma unroll
    for (int e = 0; e < 4; ++e) ea_j[rb][e] = ea_sh[rb * 16 + g * 4 + e];

  float invr[4];  // invr[cb] = 1/(n+eps) for row i = cb*16+m (all g agree)
#pragma unroll
  for (int cb = 0; cb < 4; ++cb) {
    const int i = cb * 16 + m;
    const float ebv = eb_sh[i];
    float rs = 0.f;
#pragma unroll
    for (int rb = 0; rb < 4; ++rb) {
      unsigned long long wp = 0ull;  // 4 packed bf16 (j = rb*16+g*4 .. +3)
      if (rb <= cb) {
#pragma unroll
        for (int e = 0; e < 4; ++e) {
          const int j = rb * 16 + g * 4 + e;
          const float val = (j <= i) ? st[rb][cb][e] * ea_j[rb][e] * ebv : 0.f;
          rs += val;
          wp |= (unsigned long long)bfbits(val) << (16 * e);
        }
      }
      // zero-fill masked tiles too: mm2 fragment reads cover the full row
      *(unsigned long long*)(tile + swz(i, rb * 16 + g * 4)) = wp;
    }
    rs += __shfl_xor(rs, 16, 64);
    rs += __shfl_xor(rs, 32, 64);
    const float n = fmaxf(fabsf(rs), em_sh[i]);
    invr[cb] = 1.f / (n + 1e-6f);
  }

  // ---- mm2 (per-ib) : H^T = V^T * C^T, then scale + store -----------------
#pragma unroll
  for (int ib = 0; ib < 4; ++ib) {
    const int i = ib * 16 + m;
    const bf16x8 c0 = *(const bf16x8*)(tile + swz(i, g * 8));
    f32x4 acc[4];
#pragma unroll
    for (int db = 0; db < 4; ++db) {
      f32x4 z = {0.f, 0.f, 0.f, 0.f};
      acc[db] = __builtin_amdgcn_mfma_f32_16x16x32_bf16(vfr[db][0], c0, z, 0, 0, 0);
    }
    if (ib >= 2) {
      const bf16x8 c1 = *(const bf16x8*)(tile + swz(i, 32 + g * 8));
#pragma unroll
      for (int db = 0; db < 4; ++db)
        acc[db] = __builtin_amdgcn_mfma_f32_16x16x32_bf16(vfr[db][1], c1, acc[db], 0, 0, 0);
    }
    const float iv = invr[ib];
    float* op = out + cbase + i * 64 + g * 4;
#pragma unroll
    for (int db = 0; db < 4; ++db) {
      const f32x4 hv = acc[db];
      *(float4*)(op + db * 16) =
          make_float4(hv[0] * iv, hv[1] * iv, hv[2] * iv, hv[3] * iv);
    }
  }
}

}  // namespace

extern "C" void kernel_launch(void* const* d_in, const int* in_sizes, int n_in,
                              void* d_out, int out_size, void* d_ws,
                              size_t ws_size, hipStream_t stream) {
  const float* q = (const float*)d_in[0];
  const float* k = (const float*)d_in[1];
  const float* v = (const float*)d_in[2];
  const float* ig = (const float*)d_in[3];
  const float* fg = (const float*)d_in[4];
  float* out = (float*)d_out;

  const int total = in_sizes[0];         // B*NH*S*DH
  const int nchunks = total / (L * DH);  // 2048
  mlstm_mfma<<<dim3(nchunks), dim3(64), 0, stream>>>(q, k, v, ig, fg, out);
}